// Round 14
// baseline (167.233 us; speedup 1.0000x reference)
//
#include <hip/hip_runtime.h>

#define L 9216
#define CNTF 73728.0f

// ws float-index offsets
#define F_DENOM 1024
#define F_CTX 3072             // denom+ctx = [1024, 68608)
#define F_STATS 68608          // 8192 f32 partials [ten][s 2048 | ss 2048]; dead after wfolds
// ws byte offsets
#define B_M2 274432u           // per-n 128KB pre-swizzled bf16 M2 (aliases stats partials)
#define B_QSM 38023168u        // qsmT [8 n][9216 l][256 hk] bf16

// d_out byte aliases (dead until gemm2 overwrites everything)
#define O_WF 0u                // kv-interleaved image (256KB) then Wq' (128KB)
#define O_BIAS 393216u         // 768 f32: kv-interleaved bias[512], bq[256]

typedef float floatx4 __attribute__((ext_vector_type(4)));
typedef __bf16 bf16x8 __attribute__((ext_vector_type(8)));

__device__ __forceinline__ unsigned short f2bf(float f){
  return __builtin_bit_cast(unsigned short, (__bf16)f);   // RNE, compiler cvt
}
__device__ __forceinline__ unsigned pack2(float lo, float hi){
  return (unsigned)f2bf(lo) | ((unsigned)f2bf(hi) << 16); // -> v_cvt_pk_bf16_f32
}
__device__ __forceinline__ int swz(int r){ return (r ^ (r >> 4)) & 7; }
__device__ __forceinline__ int sw4(int r){ return (r ^ (r >> 4)) & 15; }

__device__ __forceinline__ void gload16(const void* g, void* l){
  __builtin_amdgcn_global_load_lds(
      (const __attribute__((address_space(1))) unsigned*)g,
      (__attribute__((address_space(3))) unsigned*)l, 16, 0, 0);
}

// ---- stats body: one row, 9 float4/thread, loads pinned before accs ----
__device__ __forceinline__ void stats_row(const float* __restrict__ rowp,
                                          float* __restrict__ outs,
                                          float* __restrict__ outq,
                                          float* __restrict__ red, int t){
  const float4* p = (const float4*)rowp;
  float4 v[9];
  #pragma unroll
  for (int j = 0; j < 9; ++j) v[j] = p[t + 256*j];
  __builtin_amdgcn_sched_barrier(0);   // all 9 loads issued before any use
  float s = 0.f, ss = 0.f;
  #pragma unroll
  for (int j = 0; j < 9; ++j){
    s  += v[j].x + v[j].y + v[j].z + v[j].w;
    ss += v[j].x*v[j].x + v[j].y*v[j].y + v[j].z*v[j].z + v[j].w*v[j].w;
  }
  #pragma unroll
  for (int off = 1; off < 64; off <<= 1){
    s += __shfl_xor(s, off); ss += __shfl_xor(ss, off);
  }
  int w = t >> 6;
  if ((t & 63) == 0){ red[w] = s; red[4 + w] = ss; }
  __syncthreads();
  if (t == 0){
    *outs = red[0]+red[1]+red[2]+red[3];
    *outq = red[4]+red[5]+red[6]+red[7];
  }
}

// ------- BN stats for kv only (q-stats run hetero inside k_fkv) -------
__global__ __launch_bounds__(256) void k_statskv(const float* __restrict__ kv,
                                                 float* __restrict__ ws){
  __shared__ float red[8];
  int b = blockIdx.x, t = threadIdx.x;     // 2048 blocks: row = n*256 + c
  stats_row(kv + (size_t)b*L, &ws[F_STATS + 4096 + b],
            &ws[F_STATS + 4096 + 2048 + b], red, t);
}

// ---- fold BN into Wk,Wv (2 blocks); reduce kv partials; zero denom/ctx
__global__ __launch_bounds__(256) void k_wfoldkv(const float* __restrict__ W0,
    const float* __restrict__ W1, float* __restrict__ ws,
    const float* __restrict__ kg, const float* __restrict__ kb,
    char* __restrict__ outa){
  __shared__ float sc[256], sh[256];
  int b = blockIdx.x, r = threadIdx.x;
  {
    float s = 0.f, ssum = 0.f;
    #pragma unroll
    for (int n = 0; n < 8; ++n){
      s    += ws[F_STATS + 4096 + n*256 + r];
      ssum += ws[F_STATS + 4096 + 2048 + n*256 + r];
    }
    float m = s * (1.0f/CNTF);
    float vv = ssum * (1.0f/CNTF) - m*m;
    float scv = rsqrtf(vv + 1e-3f) * kg[r];
    sc[r] = scv; sh[r] = kb[r] - m*scv;
  }
  // zero denom + ctx accumulators
  for (int j = 0; j < 132; ++j){
    int i = j*512 + b*256 + r;
    if (i < 67584) ws[F_DENOM + i] = 0.0f;
  }
  __syncthreads();
  const float* W = (b == 0) ? W0 : W1;
  const float* wrow = W + (size_t)r * 256;
  int h = r >> 5;
  int imgrow = (h >> 1)*128 + (h & 1)*64 + b*32 + (r & 31);
  char* chunk = outa + O_WF;
  int opl = imgrow >> 7, rl = imgrow & 127;
  float bias = 0.f;
  for (int kc = 0; kc < 4; ++kc){
    unsigned pk[8][4];
    #pragma unroll
    for (int g = 0; g < 8; ++g){
      float v[8];
      #pragma unroll
      for (int m = 0; m < 8; ++m){
        int k = kc*64 + g*8 + m;
        float w = wrow[k];
        v[m] = w * sc[k];
        bias = fmaf(w, sh[k], bias);
      }
      pk[g][0] = pack2(v[0], v[1]); pk[g][1] = pack2(v[2], v[3]);
      pk[g][2] = pack2(v[4], v[5]); pk[g][3] = pack2(v[6], v[7]);
    }
    #pragma unroll
    for (int g = 0; g < 8; ++g){
      int idx = (opl*4 + kc)*1024 + rl*8 + (g ^ swz(rl));
      *(uint4*)(chunk + (size_t)idx*16) =
          make_uint4(pk[g][0], pk[g][1], pk[g][2], pk[g][3]);
    }
  }
  ((float*)(outa + O_BIAS))[imgrow] = bias;
}

// ---- fold BN into Wq (1 block), after q-stats from hetero fkv blocks --
__global__ __launch_bounds__(256) void k_wfoldq(const float* __restrict__ W2,
    float* __restrict__ ws,
    const float* __restrict__ qg, const float* __restrict__ qb,
    char* __restrict__ outa){
  __shared__ float sc[256], sh[256];
  int r = threadIdx.x;
  {
    float s = 0.f, ssum = 0.f;
    #pragma unroll
    for (int n = 0; n < 8; ++n){
      s    += ws[F_STATS + n*256 + r];
      ssum += ws[F_STATS + 2048 + n*256 + r];
    }
    float m = s * (1.0f/CNTF);
    float vv = ssum * (1.0f/CNTF) - m*m;
    float scv = rsqrtf(vv + 1e-3f) * qg[r];
    sc[r] = scv; sh[r] = qb[r] - m*scv;
  }
  __syncthreads();
  const float* wrow = W2 + (size_t)r * 256;
  char* chunk = outa + O_WF + 262144;
  int opl = r >> 7, rl = r & 127;
  float bias = 0.f;
  for (int kc = 0; kc < 4; ++kc){
    unsigned pk[8][4];
    #pragma unroll
    for (int g = 0; g < 8; ++g){
      float v[8];
      #pragma unroll
      for (int m = 0; m < 8; ++m){
        int k = kc*64 + g*8 + m;
        float w = wrow[k];
        v[m] = w * sc[k];
        bias = fmaf(w, sh[k], bias);
      }
      pk[g][0] = pack2(v[0], v[1]); pk[g][1] = pack2(v[2], v[3]);
      pk[g][2] = pack2(v[4], v[5]); pk[g][3] = pack2(v[6], v[7]);
    }
    #pragma unroll
    for (int g = 0; g < 8; ++g){
      int idx = (opl*4 + kc)*1024 + rl*8 + (g ^ swz(rl));
      *(uint4*)(chunk + (size_t)idx*16) =
          make_uint4(pk[g][0], pk[g][1], pk[g][2], pk[g][3]);
    }
  }
  ((float*)(outa + O_BIAS))[512 + r] = bias;
}

// ---- fused KV projection + exp + context/denominator accumulation ----
// Grid 4352: blocks 0..2303 = fkv (xcd decode as before); blocks >=2304 =
// hetero q-stats rows (co-resident in fkv's idle wave slots).
__global__ __launch_bounds__(256, 2) void k_fkv(
    const char* __restrict__ Af, const float* __restrict__ kv,
    const float* __restrict__ q_in,
    const float* __restrict__ bias, float* __restrict__ ws)
{
  __shared__ __align__(16) ushort SH[128*128];   // 32 KB
  const int t = threadIdx.x;
  const int bid = blockIdx.x;

  if (bid >= 2304){
    int sb = bid - 2304;                         // 0..2047: q row
    stats_row(q_in + (size_t)sb*L, &ws[F_STATS + sb],
              &ws[F_STATS + 2048 + sb], (float*)SH, t);
    return;
  }

  ushort* As = SH;                                // 16 KB swizzled
  ushort* Bs = SH + 128*64;                       // 16 KB swizzled
  char*   EV = (char*)SH;                         // 32 KB swizzled (sw4)
  const int lane = t & 63, wid = t >> 6;
  const int wr = wid >> 1, wc = wid & 1;
  const int xcd = bid & 7, seq = bid >> 3;
  const int op = seq & 3;
  const int lpi = (seq >> 2) & 3;
  const int gid = xcd * 18 + (seq >> 4);
  const int lpg = gid % 18, n = gid / 18;
  const int l0 = (lpg*4 + lpi) * 128;
  const char* Achunk = Af + (size_t)op * 65536;
  const int cpair = t >> 3, lg = t & 7;
  const int lcol = lane & 15, lhi = lane >> 4;
  const int lrow4 = lhi * 4;

  float bv[4];
  #pragma unroll
  for (int of = 0; of < 4; ++of)
    bv[of] = bias[op*128 + wr*64 + of*16 + lcol];

  floatx4 c16[2] = {};            // ctx acc: head wr, v-half wc
  floatx4 acc[4][4] = {};         // [lf][of]: rows=l, cols=o (swapped mfma)
  for (int kc = 0; kc < 4; ++kc){
    {
      const char* src = Achunk + kc*16384 + ((size_t)(wid*4*64 + lane))*16;
      ushort* dst = As + wid*4*512;
      gload16(src,        dst);
      gload16(src + 1024, dst + 512);
      gload16(src + 2048, dst + 1024);
      gload16(src + 3072, dst + 1536);
    }
    unsigned bu[16];
    {
      const float* Xa = kv + ((size_t)(n*256 + kc*64 + 2*cpair))*L + l0 + lg*16;
      const float* Xb = Xa + L;
      #pragma unroll
      for (int q = 0; q < 4; ++q){
        float4 a = ((const float4*)Xa)[q];
        float4 b = ((const float4*)Xb)[q];
        bu[4*q+0] = pack2(a.x, b.x);
        bu[4*q+1] = pack2(a.y, b.y);
        bu[4*q+2] = pack2(a.z, b.z);
        bu[4*q+3] = pack2(a.w, b.w);
      }
    }
    {
      int g = cpair >> 2, d = cpair & 3;
      #pragma unroll
      for (int j = 0; j < 16; ++j){
        int ll = lg*16 + j;
        *(unsigned*)((char*)Bs + ll*128 + ((g ^ swz(ll))*16) + d*4) = bu[j];
      }
    }
    __syncthreads();
    #pragma unroll
    for (int ks = 0; ks < 2; ++ks){
      bf16x8 af[4], bfr[4];
      #pragma unroll
      for (int mf = 0; mf < 4; ++mf){
        int row = wr*64 + mf*16 + lcol;
        int gq = (ks*4 + lhi) ^ swz(row);
        af[mf] = *(const bf16x8*)(As + row*64 + gq*8);
      }
      #pragma unroll
      for (int nf = 0; nf < 4; ++nf){
        int ll = wc*64 + nf*16 + lcol;
        int gq = (ks*4 + lhi) ^ swz(ll);
        bfr[nf] = *(const bf16x8*)(Bs + ll*64 + gq*8);
      }
      #pragma unroll
      for (int lf = 0; lf < 4; ++lf)
        #pragma unroll
        for (int of = 0; of < 4; ++of)
          acc[lf][of] = __builtin_amdgcn_mfma_f32_16x16x32_bf16(bfr[lf], af[of], acc[lf][of], 0, 0, 0);
    }
    __syncthreads();
  }

  // bias; exp for key cols (of 0,1); vals just biased
  #pragma unroll
  for (int lf = 0; lf < 4; ++lf)
    #pragma unroll
    for (int of = 0; of < 4; ++of)
      #pragma unroll
      for (int r = 0; r < 4; ++r){
        if (of < 2) acc[lf][of][r] = __expf(acc[lf][of][r] + bv[of]);
        else        acc[lf][of][r] += bv[of];
      }
  // denominator: sum over this wave's 64 l per key (of, lcol)
  #pragma unroll
  for (int of = 0; of < 2; ++of){
    float s = 0.f;
    #pragma unroll
    for (int lf = 0; lf < 4; ++lf)
      #pragma unroll
      for (int r = 0; r < 4; ++r)
        s += acc[lf][of][r];
    s += __shfl_xor(s, 16);
    s += __shfl_xor(s, 32);
    if (lhi == 0)
      atomicAdd(ws + F_DENOM + (size_t)((n*8) + op*2 + wr)*32 + of*16 + lcol, s);
  }
  // scatter E/V tile to swizzled LDS (bf16), packed b32 writes
  #pragma unroll
  for (int of = 0; of < 4; ++of){
    int row = wr*64 + of*16 + lcol;
    #pragma unroll
    for (int lf = 0; lf < 4; ++lf){
      int col = wc*64 + lf*16 + lrow4;
      int g = (col >> 3) ^ sw4(row);
      char* p = EV + row*256 + g*16 + (col & 7)*2;
      *(unsigned*)p       = pack2(acc[lf][of][0], acc[lf][of][1]);
      *(unsigned*)(p + 4) = pack2(acc[lf][of][2], acc[lf][of][3]);
    }
  }
  __syncthreads();
  // ctx += E (32 x 128) x V^T (128 x 32) for head wr, v-half wc
  #pragma unroll
  for (int kk = 0; kk < 4; ++kk){
    int gk = (kk*32 + lhi*8) >> 3;
    bf16x8 aE0, aE1, bV;
    {
      int row = wr*64 + lcol;
      aE0 = *(const bf16x8*)(EV + row*256 + ((gk ^ sw4(row))*16));
    }
    {
      int row = wr*64 + 16 + lcol;
      aE1 = *(const bf16x8*)(EV + row*256 + ((gk ^ sw4(row))*16));
    }
    {
      int row = wr*64 + 32 + wc*16 + lcol;
      bV = *(const bf16x8*)(EV + row*256 + ((gk ^ sw4(row))*16));
    }
    c16[0] = __builtin_amdgcn_mfma_f32_16x16x32_bf16(aE0, bV, c16[0], 0, 0, 0);
    c16[1] = __builtin_amdgcn_mfma_f32_16x16x32_bf16(aE1, bV, c16[1], 0, 0, 0);
  }

  float* ctxp = ws + F_CTX + (size_t)((n*8) + op*2 + wr)*1024;
  #pragma unroll
  for (int i0 = 0; i0 < 2; ++i0)
    #pragma unroll
    for (int r = 0; r < 4; ++r)
      atomicAdd(ctxp + (i0*16 + lrow4 + r)*32 + wc*16 + lcol, c16[i0][r]);
}

// ---------------- MFMA GEMM (+ fused M2 blocks in MODE 1) ------------
template<int MODE>
__global__ __launch_bounds__(256, 3) void k_gemm(
    const char* __restrict__ Af, size_t a_nstride,
    const void* __restrict__ Bsrc,
    const float* __restrict__ bias,
    void* __restrict__ outp, const float* __restrict__ xres,
    const float* __restrict__ Wp, float* __restrict__ wsf)
{
  __shared__ __align__(16) ushort SH[128*128];   // 32 KB: As | Bs; Lst/cn alias
  ushort* As = SH;
  ushort* Bs = SH + 128*64;
  const int t = threadIdx.x;
  const int bid = blockIdx.x;

  if (MODE == 1 && bid >= 1152){
    // ---- fused M2: per-(n,h) 256x32 = Wp x ctx_norm^T, pre-swizzled bf16
    float (*cn)[33] = (float(*)[33])SH;
    int nh = bid - 1152;
    int n = nh >> 3, h = nh & 7;
    #pragma unroll
    for (int jj = 0; jj < 4; ++jj){
      int i = jj*256 + t;
      int k = i >> 5, v = i & 31;
      cn[k][v] = wsf[F_CTX + (size_t)nh*1024 + i] / wsf[F_DENOM + nh*32 + k];
    }
    __syncthreads();
    int c = t;
    const float* wrow = Wp + (size_t)c*256 + h*32;
    float w[32];
    #pragma unroll
    for (int v = 0; v < 32; ++v) w[v] = wrow[v];
    float s[32];
    #pragma unroll
    for (int k = 0; k < 32; ++k){
      float a = 0.f;
      #pragma unroll
      for (int v = 0; v < 32; ++v) a = fmaf(w[v], cn[k][v], a);
      s[k] = a;
    }
    char* base = (char*)wsf + B_M2 + (size_t)n*131072;
    int opl = c >> 7, rl = c & 127, kc = h >> 1;
    #pragma unroll
    for (int gg = 0; gg < 4; ++gg){
      int g = (h & 1)*4 + gg;
      uint4 u = make_uint4(pack2(s[gg*8+0], s[gg*8+1]), pack2(s[gg*8+2], s[gg*8+3]),
                           pack2(s[gg*8+4], s[gg*8+5]), pack2(s[gg*8+6], s[gg*8+7]));
      *(uint4*)(base + (size_t)((opl*4 + kc)*1024 + rl*8 + (g ^ swz(rl)))*16) = u;
    }
    return;
  }

  const int lane = t & 63, wid = t >> 6;
  const int wr = wid >> 1, wc = wid & 1;
  const int xcd = bid & 7, seq = bid >> 3;
  const int op = seq & 1;
  const int gid = xcd * 72 + (seq >> 1);
  const int lp = gid % 72, n = gid / 72;
  const int l0 = lp * 128, o0 = op * 128;
  const char* Achunk = Af + (size_t)n * a_nstride + (size_t)op * 65536;
  const char* Bn = (const char*)Bsrc + (size_t)n * 4718592;
  const int cpair = t >> 3, lg = t & 7;
  const int lcol = lane & 15, lhi = lane >> 4;
  const int r8 = lane >> 3, s8 = lane & 7;

  floatx4 acc[4][4] = {};

  for (int kc = 0; kc < 4; ++kc) {
    {
      const char* src = Achunk + kc*16384 + ((size_t)(wid*4*64 + lane))*16;
      ushort* dst = As + wid*4*512;
      gload16(src,        dst);
      gload16(src + 1024, dst + 512);
      gload16(src + 2048, dst + 1024);
      gload16(src + 3072, dst + 1536);
    }
    if (MODE == 2) {
      #pragma unroll
      for (int i = 0; i < 4; ++i){
        int rw = wid*32 + i*8 + r8;
        const char* src = Bn + (size_t)(l0 + rw)*512 + kc*128 + ((s8 ^ swz(rw))*16);
        gload16(src, Bs + (wid*32 + i*8)*64);
      }
    } else {
      unsigned bu[16];
      const float* Xa = (const float*)Bsrc + ((size_t)(n*256 + kc*64 + 2*cpair))*L + l0 + lg*16;
      const float* Xb = Xa + L;
      #pragma unroll
      for (int q = 0; q < 4; ++q) {
        float4 a = ((const float4*)Xa)[q];
        float4 b = ((const float4*)Xb)[q];
        bu[4*q+0] = pack2(a.x, b.x);
        bu[4*q+1] = pack2(a.y, b.y);
        bu[4*q+2] = pack2(a.z, b.z);
        bu[4*q+3] = pack2(a.w, b.w);
      }
      int g = cpair >> 2, d = cpair & 3;
      #pragma unroll
      for (int j = 0; j < 16; ++j){
        int ll = lg*16 + j;
        *(unsigned*)((char*)Bs + ll*128 + ((g ^ swz(ll))*16) + d*4) = bu[j];
      }
    }
    __syncthreads();
    #pragma unroll
    for (int ks = 0; ks < 2; ++ks) {
      bf16x8 af[4], bfr[4];
      #pragma unroll
      for (int mf = 0; mf < 4; ++mf) {
        int row = wr*64 + mf*16 + lcol;
        int gq = (ks*4 + lhi) ^ swz(row);
        af[mf] = *(const bf16x8*)(As + row*64 + gq*8);
      }
      #pragma unroll
      for (int nf = 0; nf < 4; ++nf) {
        int ll = wc*64 + nf*16 + lcol;
        int gq = (ks*4 + lhi) ^ swz(ll);
        bfr[nf] = *(const bf16x8*)(Bs + ll*64 + gq*8);
      }
      #pragma unroll
      for (int mf = 0; mf < 4; ++mf)
        #pragma unroll
        for (int nf = 0; nf < 4; ++nf)
          acc[mf][nf] = __builtin_amdgcn_mfma_f32_16x16x32_bf16(af[mf], bfr[nf], acc[mf][nf], 0, 0, 0);
    }
    __syncthreads();
  }

  const int lrow4 = lhi * 4;

  if (MODE == 1) {
    #pragma unroll
    for (int mf = 0; mf < 4; ++mf)
      #pragma unroll
      for (int r = 0; r < 4; ++r) {
        float bv = bias[o0 + wr*64 + mf*16 + lrow4 + r];
        #pragma unroll
        for (int nf = 0; nf < 4; ++nf)
          acc[mf][nf][r] = __expf(acc[mf][nf][r] + bv);
      }
    #pragma unroll
    for (int hg = 0; hg < 2; ++hg) {
      #pragma unroll
      for (int nf = 0; nf < 4; ++nf) {
        float s = 0.f;
        #pragma unroll
        for (int mh = 0; mh < 2; ++mh)
          #pragma unroll
          for (int r = 0; r < 4; ++r)
            s += acc[hg*2+mh][nf][r];
        s += __shfl_xor(s, 16);
        s += __shfl_xor(s, 32);
        float inv = 1.0f / s;
        #pragma unroll
        for (int mh = 0; mh < 2; ++mh)
          #pragma unroll
          for (int r = 0; r < 4; ++r)
            acc[hg*2+mh][nf][r] *= inv;
      }
    }
    // transpose through LDS, store [n][l][hk] bf16 with uint4 writes
    ushort* Lst = SH;
    #pragma unroll
    for (int mf = 0; mf < 4; ++mf){
      int ol = wr*64 + mf*16 + lrow4;
      int och = ol >> 3;
      #pragma unroll
      for (int nf = 0; nf < 4; ++nf){
        int ll = wc*64 + nf*16 + lcol;
        unsigned w0 = pack2(acc[mf][nf][0], acc[mf][nf][1]);
        unsigned w1 = pack2(acc[mf][nf][2], acc[mf][nf][3]);
        char* p = (char*)Lst + ll*256 + ((och ^ sw4(ll))*16) + (ol & 7)*2;
        *(unsigned*)p = w0;
        *(unsigned*)(p + 4) = w1;
      }
    }
    __syncthreads();
    char* ob = (char*)outp + (size_t)(n*9216 + l0)*512 + o0*2;
    #pragma unroll
    for (int j = 0; j < 8; ++j){
      int flat = j*256 + t;
      int l = flat >> 4, seg = flat & 15;
      uint4 v = *(const uint4*)((const char*)Lst + l*256 + ((seg ^ sw4(l))*16));
      *(uint4*)(ob + (size_t)l*512 + seg*16) = v;
    }
  }

  if (MODE == 2) {
    float* outf = (float*)outp;
    #pragma unroll
    for (int mf = 0; mf < 4; ++mf)
      #pragma unroll
      for (int r = 0; r < 4; ++r) {
        int orow = o0 + wr*64 + mf*16 + lrow4 + r;
        size_t base = ((size_t)n*256 + orow)*L + l0 + wc*64 + lcol;
        #pragma unroll
        for (int nf = 0; nf < 4; ++nf) {
          size_t gi = base + (size_t)nf*16;
          outf[gi] = acc[mf][nf][r] + xres[gi];
        }
      }
  }
}

extern "C" void kernel_launch(void* const* d_in, const int* in_sizes, int n_in,
                              void* d_out, int out_size, void* d_ws, size_t ws_size,
                              hipStream_t stream)
{
  const float* q_in = (const float*)d_in[0];
  const float* kv   = (const float*)d_in[1];
  const float* Wq   = (const float*)d_in[2];
  const float* Wk   = (const float*)d_in[3];
  const float* Wv   = (const float*)d_in[4];
  const float* Wp   = (const float*)d_in[5];
  const float* qg   = (const float*)d_in[6];
  const float* qb   = (const float*)d_in[7];
  const float* kg   = (const float*)d_in[8];
  const float* kb   = (const float*)d_in[9];
  float* out = (float*)d_out;
  float* wsf = (float*)d_ws;
  char*  outa = (char*)d_out;
  const float* biasf = (const float*)(outa + O_BIAS);

  k_statskv<<<dim3(2048), dim3(256), 0, stream>>>(kv, wsf);
  k_wfoldkv<<<dim3(2),   dim3(256), 0, stream>>>(Wk, Wv, wsf, kg, kb, outa);
  k_fkv    <<<dim3(4352), dim3(256), 0, stream>>>(outa + O_WF, kv, q_in, biasf, wsf);
  k_wfoldq <<<dim3(1),   dim3(256), 0, stream>>>(Wq, wsf, qg, qb, outa);
  k_gemm<1><<<dim3(1216), dim3(256), 0, stream>>>(outa + O_WF + 262144, 0, q_in,
      biasf + 512, (char*)d_ws + B_QSM, nullptr, Wp, wsf);
  k_gemm<2><<<dim3(1152), dim3(256), 0, stream>>>((char*)d_ws + B_M2, 131072,
      (char*)d_ws + B_QSM, nullptr, out, q_in, nullptr, wsf);
}

// Round 15
// 150.211 us; speedup vs baseline: 1.1133x; 1.1133x over previous
//
#include <hip/hip_runtime.h>

#define L 9216
#define CNTF 73728.0f

// ws float-index offsets
#define F_DENOM 1024
#define F_CTX 3072             // denom+ctx = [1024, 68608)
#define F_STATS 68608          // 8192 f32 partials [ten][s 2048 | ss 2048]; dead after wfold
// ws byte offsets
#define B_M2 274432u           // per-n 128KB pre-swizzled bf16 M2 (aliases stats partials)
#define B_QSM 38023168u        // qsmT [8 n][9216 l][256 hk] bf16

// d_out byte aliases (dead until gemm2 overwrites everything)
#define O_WF 0u                // kv-interleaved image (256KB) then Wq' (128KB)
#define O_BIAS 393216u         // 768 f32: kv-interleaved bias[512], bq[256]

typedef float floatx4 __attribute__((ext_vector_type(4)));
typedef __bf16 bf16x8 __attribute__((ext_vector_type(8)));

__device__ __forceinline__ unsigned short f2bf(float f){
  return __builtin_bit_cast(unsigned short, (__bf16)f);   // RNE, compiler cvt
}
__device__ __forceinline__ unsigned pack2(float lo, float hi){
  return (unsigned)f2bf(lo) | ((unsigned)f2bf(hi) << 16); // -> v_cvt_pk_bf16_f32
}
__device__ __forceinline__ int swz(int r){ return (r ^ (r >> 4)) & 7; }
__device__ __forceinline__ int sw4(int r){ return (r ^ (r >> 4)) & 15; }

__device__ __forceinline__ void gload16(const void* g, void* l){
  __builtin_amdgcn_global_load_lds(
      (const __attribute__((address_space(1))) unsigned*)g,
      (__attribute__((address_space(3))) unsigned*)l, 16, 0, 0);
}

// ------- BN stats: 9 float4 loads PINNED in flight via sched_barrier ---
__global__ __launch_bounds__(256, 4) void k_stats(const float* __restrict__ q,
                                                  const float* __restrict__ kv,
                                                  float* __restrict__ ws){
  int b = blockIdx.x, t = threadIdx.x;     // 4096 blocks, one (ten,n,c) row each
  int ten = b >> 11;
  int row = b & 2047;                      // n*256 + c
  const float4* p = (const float4*)((ten ? kv : q) + (size_t)row * L);
  float4 v[9];
  #pragma unroll
  for (int j = 0; j < 9; ++j) v[j] = p[t + 256*j];
  __builtin_amdgcn_sched_barrier(0);       // force all 9 loads issued before use
  float s = 0.f, ss = 0.f;
  #pragma unroll
  for (int j = 0; j < 9; ++j){
    s  += v[j].x + v[j].y + v[j].z + v[j].w;
    ss += v[j].x*v[j].x + v[j].y*v[j].y + v[j].z*v[j].z + v[j].w*v[j].w;
  }
  #pragma unroll
  for (int off = 1; off < 64; off <<= 1){
    s += __shfl_xor(s, off); ss += __shfl_xor(ss, off);
  }
  __shared__ float r4[2][4];
  int w = t >> 6;
  if ((t & 63) == 0){ r4[0][w] = s; r4[1][w] = ss; }
  __syncthreads();
  if (t == 0){
    s  = r4[0][0]+r4[0][1]+r4[0][2]+r4[0][3];
    ss = r4[1][0]+r4[1][1]+r4[1][2]+r4[1][3];
    ws[F_STATS + ten*4096 + row] = s;            // plain store, no atomic
    ws[F_STATS + ten*4096 + 2048 + row] = ss;
  }
}

// -------- fold BN into weights; reduce stats partials; zero denom/ctx --
__global__ __launch_bounds__(256) void k_wfold(const float* __restrict__ W0,
    const float* __restrict__ W1, const float* __restrict__ W2,
    float* __restrict__ ws,
    const float* __restrict__ qg, const float* __restrict__ qb,
    const float* __restrict__ kg, const float* __restrict__ kb,
    char* __restrict__ outa){
  __shared__ float sc[256], sh[256];
  int b = blockIdx.x, r = threadIdx.x;
  int tsel = (b < 2) ? 1 : 0;                 // Wk,Wv use kv stats; Wq uses q
  {
    float s = 0.f, ssum = 0.f;
    #pragma unroll
    for (int n = 0; n < 8; ++n){
      s    += ws[F_STATS + tsel*4096 + n*256 + r];
      ssum += ws[F_STATS + tsel*4096 + 2048 + n*256 + r];
    }
    float m = s * (1.0f/CNTF);
    float vv = ssum * (1.0f/CNTF) - m*m;
    float g  = tsel ? kg[r] : qg[r];
    float be = tsel ? kb[r] : qb[r];
    float scv = rsqrtf(vv + 1e-3f) * g;
    sc[r] = scv; sh[r] = be - m*scv;
  }
  // zero denom + ctx accumulators (replaces k_init)
  for (int j = 0; j < 88; ++j){
    int i = j*768 + b*256 + r;
    if (i < 67584) ws[F_DENOM + i] = 0.0f;
  }
  __syncthreads();
  const float* W = (b == 0) ? W0 : ((b == 1) ? W1 : W2);
  const float* wrow = W + (size_t)r * 256;
  int imgrow, biasidx;
  char* chunk;
  if (b < 2){
    int h = r >> 5;
    imgrow = (h >> 1)*128 + (h & 1)*64 + b*32 + (r & 31);
    biasidx = imgrow;
    chunk = outa + O_WF;
  } else {
    imgrow = r;
    biasidx = 512 + r;
    chunk = outa + O_WF + 262144;
  }
  int opl = imgrow >> 7, rl = imgrow & 127;
  float bias = 0.f;
  for (int kc = 0; kc < 4; ++kc){
    unsigned pk[8][4];
    #pragma unroll
    for (int g = 0; g < 8; ++g){
      float v[8];
      #pragma unroll
      for (int m = 0; m < 8; ++m){
        int k = kc*64 + g*8 + m;
        float w = wrow[k];
        v[m] = w * sc[k];
        bias = fmaf(w, sh[k], bias);
      }
      pk[g][0] = pack2(v[0], v[1]); pk[g][1] = pack2(v[2], v[3]);
      pk[g][2] = pack2(v[4], v[5]); pk[g][3] = pack2(v[6], v[7]);
    }
    #pragma unroll
    for (int g = 0; g < 8; ++g){
      int idx = (opl*4 + kc)*1024 + rl*8 + (g ^ swz(rl));
      *(uint4*)(chunk + (size_t)idx*16) =
          make_uint4(pk[g][0], pk[g][1], pk[g][2], pk[g][3]);
    }
  }
  ((float*)(outa + O_BIAS))[biasidx] = bias;
}

// ---- fused KV projection + exp + context/denominator accumulation ----
// Grid 2304: xcd=bid&7, seq=bid>>3; op=seq&3, lpi=(seq>>2)&3, strip=seq>>4.
// Projection MFMA uses SWAPPED operands: acc[lf][of] rows=l, cols=o, so the
// 4 per-fragment acc elements lie along consecutive l -> packed b32 EV writes.
__global__ __launch_bounds__(256, 2) void k_fkv(
    const char* __restrict__ Af, const float* __restrict__ kv,
    const float* __restrict__ bias, float* __restrict__ ws)
{
  __shared__ __align__(16) ushort SH[128*128];   // 32 KB
  ushort* As = SH;                                // 16 KB swizzled
  ushort* Bs = SH + 128*64;                       // 16 KB swizzled
  char*   EV = (char*)SH;                         // 32 KB swizzled (sw4)
  const int t = threadIdx.x;
  const int lane = t & 63, wid = t >> 6;
  const int wr = wid >> 1, wc = wid & 1;
  const int bid = blockIdx.x;
  const int xcd = bid & 7, seq = bid >> 3;
  const int op = seq & 3;
  const int lpi = (seq >> 2) & 3;
  const int gid = xcd * 18 + (seq >> 4);
  const int lpg = gid % 18, n = gid / 18;
  const int l0 = (lpg*4 + lpi) * 128;
  const char* Achunk = Af + (size_t)op * 65536;
  const int cpair = t >> 3, lg = t & 7;
  const int lcol = lane & 15, lhi = lane >> 4;
  const int lrow4 = lhi * 4;

  float bv[4];
  #pragma unroll
  for (int of = 0; of < 4; ++of)
    bv[of] = bias[op*128 + wr*64 + of*16 + lcol];

  floatx4 c16[2] = {};            // ctx acc: head wr, v-half wc
  floatx4 acc[4][4] = {};         // [lf][of]: rows=l, cols=o (swapped mfma)
  for (int kc = 0; kc < 4; ++kc){
    {
      const char* src = Achunk + kc*16384 + ((size_t)(wid*4*64 + lane))*16;
      ushort* dst = As + wid*4*512;
      gload16(src,        dst);
      gload16(src + 1024, dst + 512);
      gload16(src + 2048, dst + 1024);
      gload16(src + 3072, dst + 1536);
    }
    unsigned bu[16];
    {
      const float* Xa = kv + ((size_t)(n*256 + kc*64 + 2*cpair))*L + l0 + lg*16;
      const float* Xb = Xa + L;
      #pragma unroll
      for (int q = 0; q < 4; ++q){
        float4 a = ((const float4*)Xa)[q];
        float4 b = ((const float4*)Xb)[q];
        bu[4*q+0] = pack2(a.x, b.x);
        bu[4*q+1] = pack2(a.y, b.y);
        bu[4*q+2] = pack2(a.z, b.z);
        bu[4*q+3] = pack2(a.w, b.w);
      }
    }
    {
      int g = cpair >> 2, d = cpair & 3;
      #pragma unroll
      for (int j = 0; j < 16; ++j){
        int ll = lg*16 + j;
        *(unsigned*)((char*)Bs + ll*128 + ((g ^ swz(ll))*16) + d*4) = bu[j];
      }
    }
    __syncthreads();
    #pragma unroll
    for (int ks = 0; ks < 2; ++ks){
      bf16x8 af[4], bfr[4];
      #pragma unroll
      for (int mf = 0; mf < 4; ++mf){
        int row = wr*64 + mf*16 + lcol;
        int gq = (ks*4 + lhi) ^ swz(row);
        af[mf] = *(const bf16x8*)(As + row*64 + gq*8);
      }
      #pragma unroll
      for (int nf = 0; nf < 4; ++nf){
        int ll = wc*64 + nf*16 + lcol;
        int gq = (ks*4 + lhi) ^ swz(ll);
        bfr[nf] = *(const bf16x8*)(Bs + ll*64 + gq*8);
      }
      #pragma unroll
      for (int lf = 0; lf < 4; ++lf)
        #pragma unroll
        for (int of = 0; of < 4; ++of)
          acc[lf][of] = __builtin_amdgcn_mfma_f32_16x16x32_bf16(bfr[lf], af[of], acc[lf][of], 0, 0, 0);
    }
    __syncthreads();
  }

  // bias; exp for key cols (of 0,1); vals just biased
  #pragma unroll
  for (int lf = 0; lf < 4; ++lf)
    #pragma unroll
    for (int of = 0; of < 4; ++of)
      #pragma unroll
      for (int r = 0; r < 4; ++r){
        if (of < 2) acc[lf][of][r] = __expf(acc[lf][of][r] + bv[of]);
        else        acc[lf][of][r] += bv[of];
      }
  // denominator: sum over this wave's 64 l per key (of, lcol)
  #pragma unroll
  for (int of = 0; of < 2; ++of){
    float s = 0.f;
    #pragma unroll
    for (int lf = 0; lf < 4; ++lf)
      #pragma unroll
      for (int r = 0; r < 4; ++r)
        s += acc[lf][of][r];
    s += __shfl_xor(s, 16);
    s += __shfl_xor(s, 32);
    if (lhi == 0)
      atomicAdd(ws + F_DENOM + (size_t)((n*8) + op*2 + wr)*32 + of*16 + lcol, s);
  }
  // scatter E/V tile to swizzled LDS (bf16), packed b32 writes
  #pragma unroll
  for (int of = 0; of < 4; ++of){
    int row = wr*64 + of*16 + lcol;
    #pragma unroll
    for (int lf = 0; lf < 4; ++lf){
      int col = wc*64 + lf*16 + lrow4;
      int g = (col >> 3) ^ sw4(row);
      char* p = EV + row*256 + g*16 + (col & 7)*2;
      *(unsigned*)p       = pack2(acc[lf][of][0], acc[lf][of][1]);
      *(unsigned*)(p + 4) = pack2(acc[lf][of][2], acc[lf][of][3]);
    }
  }
  __syncthreads();
  // ctx += E (32 x 128) x V^T (128 x 32) for head wr, v-half wc
  #pragma unroll
  for (int kk = 0; kk < 4; ++kk){
    int gk = (kk*32 + lhi*8) >> 3;
    bf16x8 aE0, aE1, bV;
    {
      int row = wr*64 + lcol;
      aE0 = *(const bf16x8*)(EV + row*256 + ((gk ^ sw4(row))*16));
    }
    {
      int row = wr*64 + 16 + lcol;
      aE1 = *(const bf16x8*)(EV + row*256 + ((gk ^ sw4(row))*16));
    }
    {
      int row = wr*64 + 32 + wc*16 + lcol;
      bV = *(const bf16x8*)(EV + row*256 + ((gk ^ sw4(row))*16));
    }
    c16[0] = __builtin_amdgcn_mfma_f32_16x16x32_bf16(aE0, bV, c16[0], 0, 0, 0);
    c16[1] = __builtin_amdgcn_mfma_f32_16x16x32_bf16(aE1, bV, c16[1], 0, 0, 0);
  }

  float* ctxp = ws + F_CTX + (size_t)((n*8) + op*2 + wr)*1024;
  #pragma unroll
  for (int i0 = 0; i0 < 2; ++i0)
    #pragma unroll
    for (int r = 0; r < 4; ++r)
      atomicAdd(ctxp + (i0*16 + lrow4 + r)*32 + wc*16 + lcol, c16[i0][r]);
}

// ---------------- MFMA GEMM (+ fused M2 blocks in MODE 1) ------------
template<int MODE>
__global__ __launch_bounds__(256, 3) void k_gemm(
    const char* __restrict__ Af, size_t a_nstride,
    const void* __restrict__ Bsrc,
    const float* __restrict__ bias,
    void* __restrict__ outp, const float* __restrict__ xres,
    const float* __restrict__ Wp, float* __restrict__ wsf)
{
  __shared__ __align__(16) ushort SH[128*128];   // 32 KB: As | Bs; Lst/cn alias
  ushort* As = SH;
  ushort* Bs = SH + 128*64;
  const int t = threadIdx.x;
  const int bid = blockIdx.x;

  if (MODE == 1 && bid >= 1152){
    // ---- fused M2: per-(n,h) 256x32 = Wp x ctx_norm^T, pre-swizzled bf16
    float (*cn)[33] = (float(*)[33])SH;
    int nh = bid - 1152;
    int n = nh >> 3, h = nh & 7;
    #pragma unroll
    for (int jj = 0; jj < 4; ++jj){
      int i = jj*256 + t;
      int k = i >> 5, v = i & 31;
      cn[k][v] = wsf[F_CTX + (size_t)nh*1024 + i] / wsf[F_DENOM + nh*32 + k];
    }
    __syncthreads();
    int c = t;
    const float* wrow = Wp + (size_t)c*256 + h*32;
    float w[32];
    #pragma unroll
    for (int v = 0; v < 32; ++v) w[v] = wrow[v];
    float s[32];
    #pragma unroll
    for (int k = 0; k < 32; ++k){
      float a = 0.f;
      #pragma unroll
      for (int v = 0; v < 32; ++v) a = fmaf(w[v], cn[k][v], a);
      s[k] = a;
    }
    char* base = (char*)wsf + B_M2 + (size_t)n*131072;
    int opl = c >> 7, rl = c & 127, kc = h >> 1;
    #pragma unroll
    for (int gg = 0; gg < 4; ++gg){
      int g = (h & 1)*4 + gg;
      uint4 u = make_uint4(pack2(s[gg*8+0], s[gg*8+1]), pack2(s[gg*8+2], s[gg*8+3]),
                           pack2(s[gg*8+4], s[gg*8+5]), pack2(s[gg*8+6], s[gg*8+7]));
      *(uint4*)(base + (size_t)((opl*4 + kc)*1024 + rl*8 + (g ^ swz(rl)))*16) = u;
    }
    return;
  }

  const int lane = t & 63, wid = t >> 6;
  const int wr = wid >> 1, wc = wid & 1;
  const int xcd = bid & 7, seq = bid >> 3;
  const int op = seq & 1;
  const int gid = xcd * 72 + (seq >> 1);
  const int lp = gid % 72, n = gid / 72;
  const int l0 = lp * 128, o0 = op * 128;
  const char* Achunk = Af + (size_t)n * a_nstride + (size_t)op * 65536;
  const char* Bn = (const char*)Bsrc + (size_t)n * 4718592;
  const int cpair = t >> 3, lg = t & 7;
  const int lcol = lane & 15, lhi = lane >> 4;
  const int r8 = lane >> 3, s8 = lane & 7;

  floatx4 acc[4][4] = {};

  for (int kc = 0; kc < 4; ++kc) {
    {
      const char* src = Achunk + kc*16384 + ((size_t)(wid*4*64 + lane))*16;
      ushort* dst = As + wid*4*512;
      gload16(src,        dst);
      gload16(src + 1024, dst + 512);
      gload16(src + 2048, dst + 1024);
      gload16(src + 3072, dst + 1536);
    }
    if (MODE == 2) {
      #pragma unroll
      for (int i = 0; i < 4; ++i){
        int rw = wid*32 + i*8 + r8;
        const char* src = Bn + (size_t)(l0 + rw)*512 + kc*128 + ((s8 ^ swz(rw))*16);
        gload16(src, Bs + (wid*32 + i*8)*64);
      }
    } else {
      unsigned bu[16];
      const float* Xa = (const float*)Bsrc + ((size_t)(n*256 + kc*64 + 2*cpair))*L + l0 + lg*16;
      const float* Xb = Xa + L;
      #pragma unroll
      for (int q = 0; q < 4; ++q) {
        float4 a = ((const float4*)Xa)[q];
        float4 b = ((const float4*)Xb)[q];
        bu[4*q+0] = pack2(a.x, b.x);
        bu[4*q+1] = pack2(a.y, b.y);
        bu[4*q+2] = pack2(a.z, b.z);
        bu[4*q+3] = pack2(a.w, b.w);
      }
      int g = cpair >> 2, d = cpair & 3;
      #pragma unroll
      for (int j = 0; j < 16; ++j){
        int ll = lg*16 + j;
        *(unsigned*)((char*)Bs + ll*128 + ((g ^ swz(ll))*16) + d*4) = bu[j];
      }
    }
    __syncthreads();
    #pragma unroll
    for (int ks = 0; ks < 2; ++ks) {
      bf16x8 af[4], bfr[4];
      #pragma unroll
      for (int mf = 0; mf < 4; ++mf) {
        int row = wr*64 + mf*16 + lcol;
        int gq = (ks*4 + lhi) ^ swz(row);
        af[mf] = *(const bf16x8*)(As + row*64 + gq*8);
      }
      #pragma unroll
      for (int nf = 0; nf < 4; ++nf) {
        int ll = wc*64 + nf*16 + lcol;
        int gq = (ks*4 + lhi) ^ swz(ll);
        bfr[nf] = *(const bf16x8*)(Bs + ll*64 + gq*8);
      }
      #pragma unroll
      for (int mf = 0; mf < 4; ++mf)
        #pragma unroll
        for (int nf = 0; nf < 4; ++nf)
          acc[mf][nf] = __builtin_amdgcn_mfma_f32_16x16x32_bf16(af[mf], bfr[nf], acc[mf][nf], 0, 0, 0);
    }
    __syncthreads();
  }

  const int lrow4 = lhi * 4;

  if (MODE == 1) {
    #pragma unroll
    for (int mf = 0; mf < 4; ++mf)
      #pragma unroll
      for (int r = 0; r < 4; ++r) {
        float bv = bias[o0 + wr*64 + mf*16 + lrow4 + r];
        #pragma unroll
        for (int nf = 0; nf < 4; ++nf)
          acc[mf][nf][r] = __expf(acc[mf][nf][r] + bv);
      }
    #pragma unroll
    for (int hg = 0; hg < 2; ++hg) {
      #pragma unroll
      for (int nf = 0; nf < 4; ++nf) {
        float s = 0.f;
        #pragma unroll
        for (int mh = 0; mh < 2; ++mh)
          #pragma unroll
          for (int r = 0; r < 4; ++r)
            s += acc[hg*2+mh][nf][r];
        s += __shfl_xor(s, 16);
        s += __shfl_xor(s, 32);
        float inv = 1.0f / s;
        #pragma unroll
        for (int mh = 0; mh < 2; ++mh)
          #pragma unroll
          for (int r = 0; r < 4; ++r)
            acc[hg*2+mh][nf][r] *= inv;
      }
    }
    // transpose through LDS, store [n][l][hk] bf16 with uint4 writes
    ushort* Lst = SH;
    #pragma unroll
    for (int mf = 0; mf < 4; ++mf){
      int ol = wr*64 + mf*16 + lrow4;
      int och = ol >> 3;
      #pragma unroll
      for (int nf = 0; nf < 4; ++nf){
        int ll = wc*64 + nf*16 + lcol;
        unsigned w0 = pack2(acc[mf][nf][0], acc[mf][nf][1]);
        unsigned w1 = pack2(acc[mf][nf][2], acc[mf][nf][3]);
        char* p = (char*)Lst + ll*256 + ((och ^ sw4(ll))*16) + (ol & 7)*2;
        *(unsigned*)p = w0;
        *(unsigned*)(p + 4) = w1;
      }
    }
    __syncthreads();
    char* ob = (char*)outp + (size_t)(n*9216 + l0)*512 + o0*2;
    #pragma unroll
    for (int j = 0; j < 8; ++j){
      int flat = j*256 + t;
      int l = flat >> 4, seg = flat & 15;
      uint4 v = *(const uint4*)((const char*)Lst + l*256 + ((seg ^ sw4(l))*16));
      *(uint4*)(ob + (size_t)l*512 + seg*16) = v;
    }
  }

  if (MODE == 2) {
    float* outf = (float*)outp;
    #pragma unroll
    for (int mf = 0; mf < 4; ++mf)
      #pragma unroll
      for (int r = 0; r < 4; ++r) {
        int orow = o0 + wr*64 + mf*16 + lrow4 + r;
        size_t base = ((size_t)n*256 + orow)*L + l0 + wc*64 + lcol;
        #pragma unroll
        for (int nf = 0; nf < 4; ++nf) {
          size_t gi = base + (size_t)nf*16;
          outf[gi] = acc[mf][nf][r] + xres[gi];
        }
      }
  }
}

extern "C" void kernel_launch(void* const* d_in, const int* in_sizes, int n_in,
                              void* d_out, int out_size, void* d_ws, size_t ws_size,
                              hipStream_t stream)
{
  const float* q_in = (const float*)d_in[0];
  const float* kv   = (const float*)d_in[1];
  const float* Wq   = (const float*)d_in[2];
  const float* Wk   = (const float*)d_in[3];
  const float* Wv   = (const float*)d_in[4];
  const float* Wp   = (const float*)d_in[5];
  const float* qg   = (const float*)d_in[6];
  const float* qb   = (const float*)d_in[7];
  const float* kg   = (const float*)d_in[8];
  const float* kb   = (const float*)d_in[9];
  float* out = (float*)d_out;
  float* wsf = (float*)d_ws;
  char*  outa = (char*)d_out;
  const float* biasf = (const float*)(outa + O_BIAS);

  k_stats<<<dim3(4096), dim3(256), 0, stream>>>(q_in, kv, wsf);
  k_wfold<<<dim3(3),    dim3(256), 0, stream>>>(Wk, Wv, Wq, wsf, qg, qb, kg, kb, outa);
  k_fkv  <<<dim3(2304), dim3(256), 0, stream>>>(outa + O_WF, kv, biasf, wsf);
  k_gemm<1><<<dim3(1216), dim3(256), 0, stream>>>(outa + O_WF + 262144, 0, q_in,
      biasf + 512, (char*)d_ws + B_QSM, nullptr, Wp, wsf);
  k_gemm<2><<<dim3(1152), dim3(256), 0, stream>>>((char*)d_ws + B_M2, 131072,
      (char*)d_ws + B_QSM, nullptr, out, q_in, nullptr, wsf);
}